// Round 6
// baseline (924.795 us; speedup 1.0000x reference)
//
#include <hip/hip_runtime.h>

// Problem constants (B=64, C=D=64, H=W=64, K=1024)
#define K_CODES 1024
#define D_DIM   64
#define N_ROWS  262144      // B*H*W
#define HW      4096        // H*W
#define CHW     262144      // C*H*W
#define N_ELEM  16777216    // B*C*H*W
#define DECAY   0.99f
#define OMD     0.01f       // 1 - DECAY
#define EPS_F   1e-05f
// Max-domain margin (acc units: m = dot - w^2/2; dist-gap = 2*acc-gap).
#define MARGIN_ACC 0.004f
#define BROWS    128        // rows per argmin block (32 per wave)
#define BFLAG_CAP 96        // per-block flagged-row cap (mean ~0.6, 128 rows max)

typedef __attribute__((ext_vector_type(8))) short bf16x8;  // 8 bf16 = 4 VGPRs
typedef __attribute__((ext_vector_type(4))) float f32x4;

// Workspace layout (bytes); [0,64) zeroed by prep each launch. 16B-aligned.
constexpr size_t OFF_LOSS    = 0;        // 1 double
constexpr size_t OFF_ADONE   = 8;        // 1 int (argmin completion count)
constexpr size_t OFF_DONE    = 12;       // 1 int (out_kernel completion count)
constexpr size_t OFF_W2F     = 64;       // 1024 f   -> 4160
constexpr size_t OFF_W2D     = 4160;     // 1024 d   -> 12352
constexpr size_t OFF_CS      = 12352;    // 1024 f   -> 16448
constexpr size_t OFF_CNT     = 16448;    // 1024 i   -> 20544 (zeroed by prep)
constexpr size_t OFF_NEWW    = 282752;   // 65536 f  -> 544896
constexpr size_t OFF_IDX     = 544896;   // 262144 i -> 1593472
constexpr size_t OFF_WFRAG   = 1986688;  // 131072 bf16 (dead after argmin)

__device__ __forceinline__ short f2bf(float f) {  // RNE float->bf16
    unsigned u = __float_as_uint(f);
    u += 0x7fffu + ((u >> 16) & 1u);
    return (short)(u >> 16);
}
__device__ __forceinline__ float bf2f(short h) {
    return __uint_as_float(((unsigned)(unsigned short)h) << 16);
}

__device__ __forceinline__ void gload_lds16(const float4* g, void* l) {
    __builtin_amdgcn_global_load_lds(
        (const __attribute__((address_space(1))) void*)g,
        (__attribute__((address_space(3))) void*)l, 16, 0, 0);
}

// One-time prep: W swizzled to bf16 hi/lo B-fragment pairs for 16x16x32 MFMA.
// Block 35 additionally zeroes the scalar counters and cnt[1024].
__global__ __launch_bounds__(256) void prep_kernel(
    const float* __restrict__ w, short* __restrict__ wfrag,
    float* __restrict__ w2f, double* __restrict__ w2d,
    int* __restrict__ scalars, int* __restrict__ cnt) {
    int t = threadIdx.x;
    if (blockIdx.x == 35) {
        if (t < 16) scalars[t] = 0;
        cnt[t] = 0; cnt[t + 256] = 0; cnt[t + 512] = 0; cnt[t + 768] = 0;
    }
    if (blockIdx.x < 32) {
        int gid = blockIdx.x * 256 + t;  // (j<<7)|(h<<6)|L
        int j = gid >> 7, h = (gid >> 6) & 1, L = gid & 63;
        int code = j * 16 + (L & 15);
        int kb = h * 32 + ((L >> 4) << 3);
        const float* wp = w + code * D_DIM + kb;
        short hi[8], lo[8];
#pragma unroll
        for (int i = 0; i < 8; ++i) {
            float v = wp[i];
            short hb = f2bf(v);
            hi[i] = hb;
            lo[i] = f2bf(v - bf2f(hb));
        }
        short* dh = wfrag + (size_t)(((j * 2 + h) * 2 + 0) * 64 + L) * 8;
        short* dl = wfrag + (size_t)(((j * 2 + h) * 2 + 1) * 64 + L) * 8;
#pragma unroll
        for (int i = 0; i < 8; ++i) { dh[i] = hi[i]; dl[i] = lo[i]; }
    } else {
        int k = (blockIdx.x - 32) * 256 + t;
        const float* wk = w + k * D_DIM;
        float sf = 0.f; double sd = 0.0;
#pragma unroll
        for (int d = 0; d < D_DIM; ++d) {
            float wv = wk[d];
            sf = fmaf(wv, wv, sf);
            sd = fma((double)wv, (double)wv, sd);
        }
        w2f[k] = sf; w2d[k] = sd;
    }
}

// Split-bf16 MFMA argmin (R4 core: 32 rows/wave, 128/block, 4 blocks/CU) with
// FUSED epilogue (R6): per-row cnt atomics, block-local fp64 refine of flagged
// rows (wave-per-row, exact, lowest-index tiebreak), and the LAST block
// (device done-counter) computes csbuf. Replaces the refine/hist/scan
// launches entirely.
__global__ __launch_bounds__(256) __attribute__((amdgpu_waves_per_eu(2, 4)))
void argmin_kernel(
    const float* __restrict__ inp, const short* __restrict__ wfrag,
    const float* __restrict__ w2f, const float* __restrict__ wgt,
    const double* __restrict__ w2d, const float* __restrict__ ema_cs,
    int* __restrict__ idx_ws, float* __restrict__ out_idx_f,
    float* __restrict__ xt, int* __restrict__ cnt,
    int* __restrict__ adone, float* __restrict__ csbuf) {
    __shared__ float w2s[K_CODES];
    __shared__ alignas(16) char smem_u[64 * 68 * 4];  // xs(17408B) / bufB(16KB) union
    __shared__ alignas(16) short bufA[8192];          // 16 KB
    __shared__ float sxr[4][64];                      // refine row stage
    __shared__ int bflag[BFLAG_CAP];
    __shared__ int bcnt, isLast;
    float (*xs)[68] = (float (*)[68])smem_u;          // +4 pad per row
    short* bufB = (short*)smem_u;

    int t = threadIdx.x;
    ((float4*)w2s)[t] = ((const float4*)w2f)[t];
    if (t == 0) bcnt = 0;

    int rowbase = blockIdx.x * BROWS;
    int b = rowbase >> 12, hwb = rowbase & (HW - 1);
    const float* xp = inp + (size_t)b * CHW + hwb;
    int lane = t & 63, wave = t >> 6;
    int q = lane >> 4, col = lane & 15;

    bf16x8 aH[2][2], aL[2][2];  // [row-set][k-half]; built in owning pass

    // Two staging passes: pass p covers block rows p*64..p*64+63.
    for (int p = 0; p < 2; ++p) {
#pragma unroll
        for (int it = 0; it < 16; ++it) {
            int d = wave * 16 + it;
            xs[lane][d] = xp[(size_t)d * HW + p * 64 + lane];  // coalesced 256B
        }
        __syncthreads();

        // xt side-product: coalesced row-major dump of these 64 rows
        float4* xt4 = (float4*)(xt + (size_t)(rowbase + p * 64) * D_DIM);
#pragma unroll
        for (int i2 = 0; i2 < 4; ++i2) {
            int c2 = t + i2 * 256;
            xt4[c2] = ((const float4*)xs[c2 >> 4])[c2 & 15];
        }

        // Waves 2p, 2p+1 own these 64 rows: build their A-fragments.
        if ((wave >> 1) == p) {
#pragma unroll
            for (int s2 = 0; s2 < 2; ++s2) {
                int rl = (wave & 1) * 32 + s2 * 16 + col;
#pragma unroll
                for (int h = 0; h < 2; ++h) {
#pragma unroll
                    for (int i = 0; i < 8; ++i) {
                        float v = xs[rl][h * 32 + q * 8 + i];
                        short hb = f2bf(v);
                        aH[s2][h][i] = hb;
                        aL[s2][h][i] = f2bf(v - bf2f(hb));
                    }
                }
            }
        }
        __syncthreads();  // all xs reads done before overwrite / bufB use
    }

    // Max-domain tracking: best = largest acc (smallest dist), best2 = 2nd.
    float best[2][4], best2[2][4];
#pragma unroll
    for (int s2 = 0; s2 < 2; ++s2)
#pragma unroll
        for (int r = 0; r < 4; ++r) { best[s2][r] = -3.4e38f; best2[s2][r] = -3.4e38f; }
    const float4* wsrc = (const float4*)wfrag;

    // Prologue: issue supertile 0 into bufA.
    {
        const float4* src = wsrc + t;
        char* nb = (char*)bufA + wave * 1024;
#pragma unroll
        for (int i2 = 0; i2 < 4; ++i2)
            gload_lds16(src + i2 * 256, nb + i2 * 4096);
    }

    for (int st = 0; st < 16; ++st) {
        asm volatile("s_waitcnt vmcnt(0)" ::: "memory");
        __syncthreads();
        if (st < 15) {
            const float4* src = wsrc + (size_t)(st + 1) * 1024 + t;
            char* nb = ((st & 1) ? (char*)bufA : (char*)bufB) + wave * 1024;
#pragma unroll
            for (int i2 = 0; i2 < 4; ++i2)
                gload_lds16(src + i2 * 256, nb + i2 * 4096);
        }
        const bf16x8* wt = (const bf16x8*)((st & 1) ? bufB : bufA);

#pragma unroll
        for (int jp = 0; jp < 2; ++jp) {
            int jA = st * 4 + jp * 2, jB = jA + 1;
            int jjA = jp * 2, jjB = jp * 2 + 1;
            bf16x8 bh0A = wt[(jjA * 4 + 0) * 64 + lane];
            bf16x8 bl0A = wt[(jjA * 4 + 1) * 64 + lane];
            bf16x8 bh1A = wt[(jjA * 4 + 2) * 64 + lane];
            bf16x8 bl1A = wt[(jjA * 4 + 3) * 64 + lane];
            bf16x8 bh0B = wt[(jjB * 4 + 0) * 64 + lane];
            bf16x8 bl0B = wt[(jjB * 4 + 1) * 64 + lane];
            bf16x8 bh1B = wt[(jjB * 4 + 2) * 64 + lane];
            bf16x8 bl1B = wt[(jjB * 4 + 3) * 64 + lane];
            float cA = -0.5f * w2s[jA * 16 + col];
            float cB = -0.5f * w2s[jB * 16 + col];
            f32x4 a0A = {cA, cA, cA, cA}, a1A = {cA, cA, cA, cA};
            f32x4 a0B = {cB, cB, cB, cB}, a1B = {cB, cB, cB, cB};
            a0A = __builtin_amdgcn_mfma_f32_16x16x32_bf16(aL[0][0], bh0A, a0A, 0, 0, 0);
            a1A = __builtin_amdgcn_mfma_f32_16x16x32_bf16(aL[1][0], bh0A, a1A, 0, 0, 0);
            a0B = __builtin_amdgcn_mfma_f32_16x16x32_bf16(aL[0][0], bh0B, a0B, 0, 0, 0);
            a1B = __builtin_amdgcn_mfma_f32_16x16x32_bf16(aL[1][0], bh0B, a1B, 0, 0, 0);
            a0A = __builtin_amdgcn_mfma_f32_16x16x32_bf16(aL[0][1], bh1A, a0A, 0, 0, 0);
            a1A = __builtin_amdgcn_mfma_f32_16x16x32_bf16(aL[1][1], bh1A, a1A, 0, 0, 0);
            a0B = __builtin_amdgcn_mfma_f32_16x16x32_bf16(aL[0][1], bh1B, a0B, 0, 0, 0);
            a1B = __builtin_amdgcn_mfma_f32_16x16x32_bf16(aL[1][1], bh1B, a1B, 0, 0, 0);
            a0A = __builtin_amdgcn_mfma_f32_16x16x32_bf16(aH[0][0], bl0A, a0A, 0, 0, 0);
            a1A = __builtin_amdgcn_mfma_f32_16x16x32_bf16(aH[1][0], bl0A, a1A, 0, 0, 0);
            a0B = __builtin_amdgcn_mfma_f32_16x16x32_bf16(aH[0][0], bl0B, a0B, 0, 0, 0);
            a1B = __builtin_amdgcn_mfma_f32_16x16x32_bf16(aH[1][0], bl0B, a1B, 0, 0, 0);
            a0A = __builtin_amdgcn_mfma_f32_16x16x32_bf16(aH[0][1], bl1A, a0A, 0, 0, 0);
            a1A = __builtin_amdgcn_mfma_f32_16x16x32_bf16(aH[1][1], bl1A, a1A, 0, 0, 0);
            a0B = __builtin_amdgcn_mfma_f32_16x16x32_bf16(aH[0][1], bl1B, a0B, 0, 0, 0);
            a1B = __builtin_amdgcn_mfma_f32_16x16x32_bf16(aH[1][1], bl1B, a1B, 0, 0, 0);
            a0A = __builtin_amdgcn_mfma_f32_16x16x32_bf16(aH[0][0], bh0A, a0A, 0, 0, 0);
            a1A = __builtin_amdgcn_mfma_f32_16x16x32_bf16(aH[1][0], bh0A, a1A, 0, 0, 0);
            a0B = __builtin_amdgcn_mfma_f32_16x16x32_bf16(aH[0][0], bh0B, a0B, 0, 0, 0);
            a1B = __builtin_amdgcn_mfma_f32_16x16x32_bf16(aH[1][0], bh0B, a1B, 0, 0, 0);
            a0A = __builtin_amdgcn_mfma_f32_16x16x32_bf16(aH[0][1], bh1A, a0A, 0, 0, 0);
            a1A = __builtin_amdgcn_mfma_f32_16x16x32_bf16(aH[1][1], bh1A, a1A, 0, 0, 0);
            a0B = __builtin_amdgcn_mfma_f32_16x16x32_bf16(aH[0][1], bh1B, a0B, 0, 0, 0);
            a1B = __builtin_amdgcn_mfma_f32_16x16x32_bf16(aH[1][1], bh1B, a1B, 0, 0, 0);
#pragma unroll
            for (int s2 = 0; s2 < 2; ++s2) {
#pragma unroll
                for (int r = 0; r < 4; ++r) {
                    float vA = (s2 ? a1A : a0A)[r];
                    float vB = (s2 ? a1B : a0B)[r];
                    float kA = __int_as_float((__float_as_int(vA) & ~63) | jA);
                    float kB = __int_as_float((__float_as_int(vB) & ~63) | jB);
                    float hi = fmaxf(kA, kB);
                    float lo = fminf(kA, kB);
                    float tm = fminf(best[s2][r], hi);
                    best2[s2][r] = fmaxf(fmaxf(tm, lo), best2[s2][r]);
                    best[s2][r]  = fmaxf(best[s2][r], hi);
                }
            }
        }
    }

    // Unpack candidate index from key bits.
    int bk[2][4];
#pragma unroll
    for (int s2 = 0; s2 < 2; ++s2)
#pragma unroll
        for (int r = 0; r < 4; ++r)
            bk[s2][r] = ((__float_as_int(best[s2][r]) & 63) << 4) | col;

#pragma unroll
    for (int m = 1; m < 16; m <<= 1) {
#pragma unroll
        for (int s2 = 0; s2 < 2; ++s2) {
#pragma unroll
            for (int r = 0; r < 4; ++r) {
                float ob  = __shfl_xor(best[s2][r], m, 64);
                float ob2 = __shfl_xor(best2[s2][r], m, 64);
                int   obk = __shfl_xor(bk[s2][r], m, 64);
                float nb2 = fmaxf(fmaxf(best2[s2][r], ob2),
                                  fminf(best[s2][r], ob));
                int   nbk = ob > best[s2][r] ? obk
                            : (best[s2][r] > ob ? bk[s2][r]
                                                : min(bk[s2][r], obk));
                best[s2][r]  = fmaxf(best[s2][r], ob);
                best2[s2][r] = nb2;
                bk[s2][r]    = nbk;
            }
        }
    }

    __syncthreads();  // bcnt=0 visible; main-loop LDS dead
    if (col == 0) {
#pragma unroll
        for (int s2 = 0; s2 < 2; ++s2) {
#pragma unroll
            for (int r = 0; r < 4; ++r) {
                int row = rowbase + wave * 32 + s2 * 16 + q * 4 + r;
                int k = bk[s2][r];
                idx_ws[row]    = k;
                out_idx_f[row] = (float)k;
                atomicAdd(&cnt[k], 1);
                if (best[s2][r] - best2[s2][r] < MARGIN_ACC) {
                    int p = atomicAdd(&bcnt, 1);
                    if (p < BFLAG_CAP) bflag[p] = (row << 10) | k;
                }
            }
        }
    }
    __syncthreads();

    // ---- inline fp64 refine of this block's flagged rows (wave-per-row) ----
    int nb = bcnt < BFLAG_CAP ? bcnt : BFLAG_CAP;
    for (int i = wave; i < nb; i += 4) {
        int e = bflag[i];
        int row = e >> 10, old = e & 1023;
        sxr[wave][lane] = xt[(size_t)row * D_DIM + lane];
        asm volatile("s_waitcnt lgkmcnt(0)" ::: "memory");

        double bd = 1.0e300; int bi = 0;
        int k0 = lane * 16;
#pragma unroll 2
        for (int c = 0; c < 16; ++c) {
            int k = k0 + c;
            const float4* wk4 = (const float4*)(wgt + (size_t)k * D_DIM);
            double dot = 0.0;
#pragma unroll
            for (int d4 = 0; d4 < 16; ++d4) {
                float4 wv = wk4[d4];
                dot = fma((double)wv.x, (double)sxr[wave][d4 * 4 + 0], dot);
                dot = fma((double)wv.y, (double)sxr[wave][d4 * 4 + 1], dot);
                dot = fma((double)wv.z, (double)sxr[wave][d4 * 4 + 2], dot);
                dot = fma((double)wv.w, (double)sxr[wave][d4 * 4 + 3], dot);
            }
            double dist = w2d[k] - 2.0 * dot;  // x^2 omitted (row-constant)
            if (dist < bd) { bd = dist; bi = k; }
        }
#pragma unroll
        for (int m = 1; m < 64; m <<= 1) {
            double od = __shfl_xor(bd, m, 64);
            int    oi = __shfl_xor(bi, m, 64);
            if (od < bd || (od == bd && oi < bi)) { bd = od; bi = oi; }
        }
        if (lane == 0 && bi != old) {
            idx_ws[row]    = bi;
            out_idx_f[row] = (float)bi;
            atomicSub(&cnt[old], 1);
            atomicAdd(&cnt[bi], 1);
        }
    }

    // ---- last block computes csbuf (Laplace-smoothed cluster sizes) ----
    __threadfence();
    __syncthreads();
    if (t == 0) isLast = (atomicAdd(adone, 1) == (int)gridDim.x - 1);
    __syncthreads();
    if (!isLast) return;

    float* red = w2s;  // reuse (dead)
    float css[4]; float mycs = 0.f;
#pragma unroll
    for (int c = 0; c < 4; ++c) {
        int k = t * 4 + c;
        int cv = atomicAdd(&cnt[k], 0);  // device-coherent read
        css[c] = ema_cs[k] * DECAY + OMD * (float)cv;
        mycs += css[c];
    }
    red[t] = mycs;
    __syncthreads();
    for (int s = 128; s > 0; s >>= 1) {
        if (t < s) red[t] += red[t + s];
        __syncthreads();
    }
    float n = red[0];
#pragma unroll
    for (int c = 0; c < 4; ++c) {
        int k = t * 4 + c;
        csbuf[k] = (css[c] + EPS_F) / (n + (float)K_CODES * EPS_F) * n;
    }
}

// dwred-direct (R6): one block per code. Ballot-scans the full idx array
// (1MB, L2-resident; wave-uniform inner loop) and wave-cooperatively gathers
// matching xt rows (coalesced 256B: lane d accumulates dim d). Each xt row is
// read exactly once device-wide. Fused EMA+normalize writes new_w directly.
// Replaces scan+scatter+sorted-gather (2 launches + 2MB intermediates).
__global__ __launch_bounds__(256) void dwred_kernel(
    const float* __restrict__ xt, const int* __restrict__ idx_ws,
    const float* __restrict__ ema_w, const float* __restrict__ csbuf,
    float* __restrict__ new_w) {
    __shared__ float red[4][64];
    int k = blockIdx.x, t = threadIdx.x;
    int lane = t & 63, wave = t >> 6;
    const int4* idx4 = (const int4*)idx_ws;  // 65536 entries

    float acc = 0.f;
    for (int it = 0; it < 256; ++it) {
        int e = wave * 16384 + it * 64 + lane;
        int4 c = idx4[e];
        int ebase = (e - lane) * 4;  // wave-uniform
        unsigned long long m;
        m = __ballot(c.x == k);
        while (m) {
            int l = __ffsll((unsigned long long)m) - 1; m &= m - 1;
            acc += xt[(size_t)(ebase + l * 4 + 0) * D_DIM + lane];
        }
        m = __ballot(c.y == k);
        while (m) {
            int l = __ffsll((unsigned long long)m) - 1; m &= m - 1;
            acc += xt[(size_t)(ebase + l * 4 + 1) * D_DIM + lane];
        }
        m = __ballot(c.z == k);
        while (m) {
            int l = __ffsll((unsigned long long)m) - 1; m &= m - 1;
            acc += xt[(size_t)(ebase + l * 4 + 2) * D_DIM + lane];
        }
        m = __ballot(c.w == k);
        while (m) {
            int l = __ffsll((unsigned long long)m) - 1; m &= m - 1;
            acc += xt[(size_t)(ebase + l * 4 + 3) * D_DIM + lane];
        }
    }
    red[wave][lane] = acc;
    __syncthreads();
    if (t < 64) {
        float dwv = red[0][t] + red[1][t] + red[2][t] + red[3][t];
        new_w[k * D_DIM + t] =
            (ema_w[k * D_DIM + t] * DECAY + OMD * dwv) / csbuf[k];
    }
}

// Gather updated codebook, straight-through output, commitment-loss partials.
// Last block (completion counter) finalizes the loss scalar.
__global__ __launch_bounds__(256) void out_kernel(
    const float* __restrict__ inp, const float* __restrict__ new_w,
    const int* __restrict__ idx_ws, float* __restrict__ out,
    double* __restrict__ loss_acc, int* __restrict__ done_cnt) {
    int row = blockIdx.x * 256 + threadIdx.x;
    int b  = row >> 12;
    int hw = row & (HW - 1);
    const float* xp = inp + (size_t)b * CHW + hw;
    float* op = out + 1 + (size_t)b * CHW + hw;  // out[0] is the loss scalar

    int k = idx_ws[row];
    const float* q = new_w + k * D_DIM;

    float lsum = 0.f;
#pragma unroll
    for (int d = 0; d < D_DIM; ++d) {
        float xv = xp[(size_t)d * HW];
        float qv = q[d];
        float diff = qv - xv;            // stop_gradient(quantized) - x
        lsum = fmaf(diff, diff, lsum);
        op[(size_t)d * HW] = xv + diff;  // x + (quantized - x)
    }

    __shared__ double lred[256];
    lred[threadIdx.x] = (double)lsum;
    __syncthreads();
    for (int s = 128; s > 0; s >>= 1) {
        if (threadIdx.x < s) lred[threadIdx.x] += lred[threadIdx.x + s];
        __syncthreads();
    }
    if (threadIdx.x == 0) {
        atomicAdd(loss_acc, lred[0]);
        __threadfence();
        int old = atomicAdd(done_cnt, 1);
        if (old == (int)gridDim.x - 1) {
            double v = atomicAdd(loss_acc, 0.0);
            out[0] = (float)(0.25 * (v / (double)N_ELEM));
        }
    }
}

extern "C" void kernel_launch(void* const* d_in, const int* in_sizes, int n_in,
                              void* d_out, int out_size, void* d_ws, size_t ws_size,
                              hipStream_t stream) {
    const float* inp    = (const float*)d_in[0];
    const float* weight = (const float*)d_in[1];
    const float* ema_cs = (const float*)d_in[2];
    const float* ema_w  = (const float*)d_in[3];
    float* out = (float*)d_out;

    char* ws = (char*)d_ws;
    double* loss_acc = (double*)(ws + OFF_LOSS);
    int*    adone    = (int*)(ws + OFF_ADONE);
    int*    done_cnt = (int*)(ws + OFF_DONE);
    float*  w2f      = (float*)(ws + OFF_W2F);
    double* w2d      = (double*)(ws + OFF_W2D);
    float*  csbuf    = (float*)(ws + OFF_CS);
    int*    cnt      = (int*)(ws + OFF_CNT);
    float*  new_w    = (float*)(ws + OFF_NEWW);
    int*    idx_ws   = (int*)(ws + OFF_IDX);
    short*  wfrag    = (short*)(ws + OFF_WFRAG);

    float* xt        = out + 1;               // scratch: overwritten by out_kernel
    float* out_idx_f = out + 1 + (size_t)N_ELEM;

    prep_kernel<<<36, 256, 0, stream>>>(weight, wfrag, w2f, w2d, (int*)ws, cnt);

    argmin_kernel<<<N_ROWS / BROWS, 256, 0, stream>>>(
        inp, wfrag, w2f, weight, w2d, ema_cs,
        idx_ws, out_idx_f, xt, cnt, adone, csbuf);

    dwred_kernel<<<K_CODES, 256, 0, stream>>>(xt, idx_ws, ema_w, csbuf, new_w);

    out_kernel<<<N_ROWS / 256, 256, 0, stream>>>(inp, new_w, idx_ws, out,
                                                 loss_acc, done_cnt);
}

// Round 7
// 433.499 us; speedup vs baseline: 2.1333x; 2.1333x over previous
//
#include <hip/hip_runtime.h>

// Problem constants (B=64, C=D=64, H=W=64, K=1024)
#define K_CODES 1024
#define D_DIM   64
#define N_ROWS  262144      // B*H*W
#define HW      4096        // H*W
#define CHW     262144      // C*H*W
#define N_ELEM  16777216    // B*C*H*W
#define DECAY   0.99f
#define OMD     0.01f       // 1 - DECAY
#define EPS_F   1e-05f
// Max-domain margin (acc units; dist-gap = 2*acc-gap). With exact cndmask
// index tracking (no mantissa packing), the split-bf16 score error is
// ~3e-4 (missing xl*wl term) + ~1e-4 (w2 fp32) + ~3e-5 (MFMA accum) —
// worst case ~7e-4. Margin 1e-3 covers it; flags ~3% of rows.
#define MARGIN_ACC 0.001f
#define FLAG_CAP 32768
#define SEG_CAP  2048       // per-code row cap (mean 256, Poisson max ~340)
#define NHB      64         // hist blocks (4096 rows each)
#define BROWS    128        // rows per argmin block (32 per wave)

typedef __attribute__((ext_vector_type(8))) short bf16x8;  // 8 bf16 = 4 VGPRs
typedef __attribute__((ext_vector_type(4))) float f32x4;

// Workspace layout (bytes); [0,64) zeroed by prep. All 16B-aligned.
// FLAGS and WFRAG temporally overlay SORT (dead before scatter writes it).
constexpr size_t OFF_LOSS    = 0;        // 1 double
constexpr size_t OFF_FLAGCNT = 8;        // 1 int
constexpr size_t OFF_DONE    = 12;       // 1 int (out_kernel completion count)
constexpr size_t OFF_W2F     = 64;       // 1024 f   -> 4160
constexpr size_t OFF_W2D     = 4160;     // 1024 d   -> 12352
constexpr size_t OFF_CS      = 12352;    // 1024 f   -> 16448
constexpr size_t OFF_GOFF    = 16448;    // 1025 i   -> 20608 (padded)
constexpr size_t OFF_NEWW    = 282752;   // 65536 f  -> 544896
constexpr size_t OFF_IDX     = 544896;   // 262144 i -> 1593472
constexpr size_t OFF_HISTB   = 1593472;  // 64x1024 i -> 1855616
constexpr size_t OFF_SORT    = 1855616;  // 262144 i -> 2904192
constexpr size_t OFF_FLAGS   = 1855616;  // 32768 i (dead after refine)
constexpr size_t OFF_WFRAG   = 1986688;  // 131072 bf16 (dead after argmin)

__device__ __forceinline__ short f2bf(float f) {  // RNE float->bf16
    unsigned u = __float_as_uint(f);
    u += 0x7fffu + ((u >> 16) & 1u);
    return (short)(u >> 16);
}
__device__ __forceinline__ float bf2f(short h) {
    return __uint_as_float(((unsigned)(unsigned short)h) << 16);
}

__device__ __forceinline__ void gload_lds16(const float4* g, void* l) {
    __builtin_amdgcn_global_load_lds(
        (const __attribute__((address_space(1))) void*)g,
        (__attribute__((address_space(3))) void*)l, 16, 0, 0);
}

// One-time prep: W swizzled to bf16 hi/lo B-fragment pairs for 16x16x32 MFMA.
// Block 35 threads 0..3 zero the scalar counters.
__global__ __launch_bounds__(256) void prep_kernel(
    const float* __restrict__ w, short* __restrict__ wfrag,
    float* __restrict__ w2f, double* __restrict__ w2d,
    int* __restrict__ zero16) {
    int t = threadIdx.x;
    if (blockIdx.x == 35 && t < 4) zero16[t] = 0;
    if (blockIdx.x < 32) {
        int gid = blockIdx.x * 256 + t;  // (j<<7)|(h<<6)|L
        int j = gid >> 7, h = (gid >> 6) & 1, L = gid & 63;
        int code = j * 16 + (L & 15);
        int kb = h * 32 + ((L >> 4) << 3);
        const float* wp = w + code * D_DIM + kb;
        short hi[8], lo[8];
#pragma unroll
        for (int i = 0; i < 8; ++i) {
            float v = wp[i];
            short hb = f2bf(v);
            hi[i] = hb;
            lo[i] = f2bf(v - bf2f(hb));
        }
        short* dh = wfrag + (size_t)(((j * 2 + h) * 2 + 0) * 64 + L) * 8;
        short* dl = wfrag + (size_t)(((j * 2 + h) * 2 + 1) * 64 + L) * 8;
#pragma unroll
        for (int i = 0; i < 8; ++i) { dh[i] = hi[i]; dl[i] = lo[i]; }
    } else {
        int k = (blockIdx.x - 32) * 256 + t;
        const float* wk = w + k * D_DIM;
        float sf = 0.f; double sd = 0.0;
#pragma unroll
        for (int d = 0; d < D_DIM; ++d) {
            float wv = wk[d];
            sf = fmaf(wv, wv, sf);
            sd = fma((double)wv, (double)wv, sd);
        }
        w2f[k] = sf; w2d[k] = sd;
    }
}

// Split-bf16 MFMA argmin (R4 core, proven 128us): 32 rows/wave, 128/block,
// 4 blocks/CU. Max-domain accumulator init (acc = dot - w^2/2, argmax).
// R7: index tracked via cmp/cndmask (exact; no mantissa packing) — R4 proved
// scoreboard VALU is not the limiter, and removing the 64-ULP packing
// perturbation lets MARGIN_ACC tighten 4x -> ~4x fewer refine flags.
__global__ __launch_bounds__(256) __attribute__((amdgpu_waves_per_eu(2, 4)))
void argmin_kernel(
    const float* __restrict__ inp, const short* __restrict__ wfrag,
    const float* __restrict__ w2f, int* __restrict__ idx_ws,
    float* __restrict__ out_idx_f, float* __restrict__ xt,
    int* __restrict__ flagcnt, int* __restrict__ flaglist) {
    __shared__ float w2s[K_CODES];
    __shared__ alignas(16) char smem_u[64 * 68 * 4];  // xs(17408B) / bufB(16KB) union
    __shared__ alignas(16) short bufA[8192];          // 16 KB
    float (*xs)[68] = (float (*)[68])smem_u;          // +4 pad per row
    short* bufB = (short*)smem_u;

    int t = threadIdx.x;
    ((float4*)w2s)[t] = ((const float4*)w2f)[t];

    int rowbase = blockIdx.x * BROWS;
    int b = rowbase >> 12, hwb = rowbase & (HW - 1);
    const float* xp = inp + (size_t)b * CHW + hwb;
    int lane = t & 63, wave = t >> 6;
    int q = lane >> 4, col = lane & 15;

    bf16x8 aH[2][2], aL[2][2];  // [row-set][k-half]; built in owning pass

    // Two staging passes: pass p covers block rows p*64..p*64+63.
    for (int p = 0; p < 2; ++p) {
#pragma unroll
        for (int it = 0; it < 16; ++it) {
            int d = wave * 16 + it;
            xs[lane][d] = xp[(size_t)d * HW + p * 64 + lane];  // coalesced 256B
        }
        __syncthreads();

        // xt side-product: coalesced row-major dump of these 64 rows
        float4* xt4 = (float4*)(xt + (size_t)(rowbase + p * 64) * D_DIM);
#pragma unroll
        for (int i2 = 0; i2 < 4; ++i2) {
            int c2 = t + i2 * 256;
            xt4[c2] = ((const float4*)xs[c2 >> 4])[c2 & 15];
        }

        // Waves 2p, 2p+1 own these 64 rows: build their A-fragments.
        if ((wave >> 1) == p) {
#pragma unroll
            for (int s2 = 0; s2 < 2; ++s2) {
                int rl = (wave & 1) * 32 + s2 * 16 + col;
#pragma unroll
                for (int h = 0; h < 2; ++h) {
#pragma unroll
                    for (int i = 0; i < 8; ++i) {
                        float v = xs[rl][h * 32 + q * 8 + i];
                        short hb = f2bf(v);
                        aH[s2][h][i] = hb;
                        aL[s2][h][i] = f2bf(v - bf2f(hb));
                    }
                }
            }
        }
        __syncthreads();  // all xs reads done before overwrite / bufB use
    }

    // Max-domain tracking: best = largest acc (smallest dist), best2 = 2nd.
    float best[2][4], best2[2][4];
    int   bj[2][4];
#pragma unroll
    for (int s2 = 0; s2 < 2; ++s2)
#pragma unroll
        for (int r = 0; r < 4; ++r) {
            best[s2][r] = -3.4e38f; best2[s2][r] = -3.4e38f; bj[s2][r] = 0;
        }
    const float4* wsrc = (const float4*)wfrag;

    // Prologue: issue supertile 0 into bufA.
    {
        const float4* src = wsrc + t;
        char* nb = (char*)bufA + wave * 1024;
#pragma unroll
        for (int i2 = 0; i2 < 4; ++i2)
            gload_lds16(src + i2 * 256, nb + i2 * 4096);
    }

    for (int st = 0; st < 16; ++st) {
        asm volatile("s_waitcnt vmcnt(0)" ::: "memory");
        __syncthreads();
        if (st < 15) {
            const float4* src = wsrc + (size_t)(st + 1) * 1024 + t;
            char* nb = ((st & 1) ? (char*)bufA : (char*)bufB) + wave * 1024;
#pragma unroll
            for (int i2 = 0; i2 < 4; ++i2)
                gload_lds16(src + i2 * 256, nb + i2 * 4096);
        }
        const bf16x8* wt = (const bf16x8*)((st & 1) ? bufB : bufA);

#pragma unroll
        for (int jp = 0; jp < 2; ++jp) {
            int jA = st * 4 + jp * 2, jB = jA + 1;
            int jjA = jp * 2, jjB = jp * 2 + 1;
            bf16x8 bh0A = wt[(jjA * 4 + 0) * 64 + lane];
            bf16x8 bl0A = wt[(jjA * 4 + 1) * 64 + lane];
            bf16x8 bh1A = wt[(jjA * 4 + 2) * 64 + lane];
            bf16x8 bl1A = wt[(jjA * 4 + 3) * 64 + lane];
            bf16x8 bh0B = wt[(jjB * 4 + 0) * 64 + lane];
            bf16x8 bl0B = wt[(jjB * 4 + 1) * 64 + lane];
            bf16x8 bh1B = wt[(jjB * 4 + 2) * 64 + lane];
            bf16x8 bl1B = wt[(jjB * 4 + 3) * 64 + lane];
            float cA = -0.5f * w2s[jA * 16 + col];
            float cB = -0.5f * w2s[jB * 16 + col];
            f32x4 a0A = {cA, cA, cA, cA}, a1A = {cA, cA, cA, cA};
            f32x4 a0B = {cB, cB, cB, cB}, a1B = {cB, cB, cB, cB};
            a0A = __builtin_amdgcn_mfma_f32_16x16x32_bf16(aL[0][0], bh0A, a0A, 0, 0, 0);
            a1A = __builtin_amdgcn_mfma_f32_16x16x32_bf16(aL[1][0], bh0A, a1A, 0, 0, 0);
            a0B = __builtin_amdgcn_mfma_f32_16x16x32_bf16(aL[0][0], bh0B, a0B, 0, 0, 0);
            a1B = __builtin_amdgcn_mfma_f32_16x16x32_bf16(aL[1][0], bh0B, a1B, 0, 0, 0);
            a0A = __builtin_amdgcn_mfma_f32_16x16x32_bf16(aL[0][1], bh1A, a0A, 0, 0, 0);
            a1A = __builtin_amdgcn_mfma_f32_16x16x32_bf16(aL[1][1], bh1A, a1A, 0, 0, 0);
            a0B = __builtin_amdgcn_mfma_f32_16x16x32_bf16(aL[0][1], bh1B, a0B, 0, 0, 0);
            a1B = __builtin_amdgcn_mfma_f32_16x16x32_bf16(aL[1][1], bh1B, a1B, 0, 0, 0);
            a0A = __builtin_amdgcn_mfma_f32_16x16x32_bf16(aH[0][0], bl0A, a0A, 0, 0, 0);
            a1A = __builtin_amdgcn_mfma_f32_16x16x32_bf16(aH[1][0], bl0A, a1A, 0, 0, 0);
            a0B = __builtin_amdgcn_mfma_f32_16x16x32_bf16(aH[0][0], bl0B, a0B, 0, 0, 0);
            a1B = __builtin_amdgcn_mfma_f32_16x16x32_bf16(aH[1][0], bl0B, a1B, 0, 0, 0);
            a0A = __builtin_amdgcn_mfma_f32_16x16x32_bf16(aH[0][1], bl1A, a0A, 0, 0, 0);
            a1A = __builtin_amdgcn_mfma_f32_16x16x32_bf16(aH[1][1], bl1A, a1A, 0, 0, 0);
            a0B = __builtin_amdgcn_mfma_f32_16x16x32_bf16(aH[0][1], bl1B, a0B, 0, 0, 0);
            a1B = __builtin_amdgcn_mfma_f32_16x16x32_bf16(aH[1][1], bl1B, a1B, 0, 0, 0);
            a0A = __builtin_amdgcn_mfma_f32_16x16x32_bf16(aH[0][0], bh0A, a0A, 0, 0, 0);
            a1A = __builtin_amdgcn_mfma_f32_16x16x32_bf16(aH[1][0], bh0A, a1A, 0, 0, 0);
            a0B = __builtin_amdgcn_mfma_f32_16x16x32_bf16(aH[0][0], bh0B, a0B, 0, 0, 0);
            a1B = __builtin_amdgcn_mfma_f32_16x16x32_bf16(aH[1][0], bh0B, a1B, 0, 0, 0);
            a0A = __builtin_amdgcn_mfma_f32_16x16x32_bf16(aH[0][1], bh1A, a0A, 0, 0, 0);
            a1A = __builtin_amdgcn_mfma_f32_16x16x32_bf16(aH[1][1], bh1A, a1A, 0, 0, 0);
            a0B = __builtin_amdgcn_mfma_f32_16x16x32_bf16(aH[0][1], bh1B, a0B, 0, 0, 0);
            a1B = __builtin_amdgcn_mfma_f32_16x16x32_bf16(aH[1][1], bh1B, a1B, 0, 0, 0);
#pragma unroll
            for (int s2 = 0; s2 < 2; ++s2) {
#pragma unroll
                for (int r = 0; r < 4; ++r) {
                    float vA = (s2 ? a1A : a0A)[r];
                    float vB = (s2 ? a1B : a0B)[r];
                    // exact sequential updates; strict > keeps lowest j on tie
                    bool gA = vA > best[s2][r];
                    best2[s2][r] = fmaxf(best2[s2][r], fminf(best[s2][r], vA));
                    best[s2][r]  = fmaxf(best[s2][r], vA);
                    bj[s2][r]    = gA ? jA : bj[s2][r];
                    bool gB = vB > best[s2][r];
                    best2[s2][r] = fmaxf(best2[s2][r], fminf(best[s2][r], vB));
                    best[s2][r]  = fmaxf(best[s2][r], vB);
                    bj[s2][r]    = gB ? jB : bj[s2][r];
                }
            }
        }
    }

    // Candidate code index = supertile*16 + col.
    int bk[2][4];
#pragma unroll
    for (int s2 = 0; s2 < 2; ++s2)
#pragma unroll
        for (int r = 0; r < 4; ++r)
            bk[s2][r] = (bj[s2][r] << 4) | col;

#pragma unroll
    for (int m = 1; m < 16; m <<= 1) {
#pragma unroll
        for (int s2 = 0; s2 < 2; ++s2) {
#pragma unroll
            for (int r = 0; r < 4; ++r) {
                float ob  = __shfl_xor(best[s2][r], m, 64);
                float ob2 = __shfl_xor(best2[s2][r], m, 64);
                int   obk = __shfl_xor(bk[s2][r], m, 64);
                float nb2 = fmaxf(fmaxf(best2[s2][r], ob2),
                                  fminf(best[s2][r], ob));
                int   nbk = ob > best[s2][r] ? obk
                            : (best[s2][r] > ob ? bk[s2][r]
                                                : min(bk[s2][r], obk));
                best[s2][r]  = fmaxf(best[s2][r], ob);
                best2[s2][r] = nb2;
                bk[s2][r]    = nbk;
            }
        }
    }

    if (col == 0) {
#pragma unroll
        for (int s2 = 0; s2 < 2; ++s2) {
#pragma unroll
            for (int r = 0; r < 4; ++r) {
                int row = rowbase + wave * 32 + s2 * 16 + q * 4 + r;
                idx_ws[row]    = bk[s2][r];
                out_idx_f[row] = (float)bk[s2][r];
                if (best[s2][r] - best2[s2][r] < MARGIN_ACC) {
                    int pos = atomicAdd(flagcnt, 1);
                    if (pos < FLAG_CAP) flaglist[pos] = row;
                }
            }
        }
    }
}

// fp64 rescan of flagged rows (exact); wave-per-row.
__global__ __launch_bounds__(256) void refine_kernel(
    const float* __restrict__ xt, const float* __restrict__ weight,
    const double* __restrict__ w2d, int* __restrict__ idx_ws,
    float* __restrict__ out_idx_f, const int* __restrict__ flagcnt,
    const int* __restrict__ flaglist) {
    __shared__ float sx[4][64];
    int cnt = *flagcnt;
    if (cnt > FLAG_CAP) cnt = FLAG_CAP;
    int t = threadIdx.x, lane = t & 63, wave = t >> 6;

    for (int r = blockIdx.x * 4 + wave; r < cnt; r += gridDim.x * 4) {
        int row = flaglist[r];
        sx[wave][lane] = xt[(size_t)row * D_DIM + lane];
        asm volatile("s_waitcnt lgkmcnt(0)" ::: "memory");

        double bd = 1.0e300; int bi = 0;
        int k0 = lane * 16;
#pragma unroll 4
        for (int c = 0; c < 16; ++c) {
            int k = k0 + c;
            const float4* wk4 = (const float4*)(weight + (size_t)k * D_DIM);
            double dot = 0.0;
#pragma unroll
            for (int d4 = 0; d4 < 16; ++d4) {
                float4 wv = wk4[d4];
                dot = fma((double)wv.x, (double)sx[wave][d4 * 4 + 0], dot);
                dot = fma((double)wv.y, (double)sx[wave][d4 * 4 + 1], dot);
                dot = fma((double)wv.z, (double)sx[wave][d4 * 4 + 2], dot);
                dot = fma((double)wv.w, (double)sx[wave][d4 * 4 + 3], dot);
            }
            double dist = w2d[k] - 2.0 * dot;  // x^2 omitted (row-constant)
            if (dist < bd) { bd = dist; bi = k; }
        }
#pragma unroll
        for (int m = 1; m < 64; m <<= 1) {
            double od = __shfl_xor(bd, m, 64);
            int    oi = __shfl_xor(bi, m, 64);
            if (od < bd || (od == bd && oi < bi)) { bd = od; bi = oi; }
        }
        if (lane == 0 && bi != idx_ws[row]) {
            idx_ws[row]    = bi;
            out_idx_f[row] = (float)bi;
        }
    }
}

// Counting sort, pass 1: per-block LDS histogram of 4096 rows -> histb[b][k].
__global__ __launch_bounds__(256) void hist_kernel(
    const int* __restrict__ idx_ws, int* __restrict__ histb) {
    __shared__ int h[K_CODES];
    int t = threadIdx.x, b = blockIdx.x;
    for (int i = t; i < K_CODES; i += 256) h[i] = 0;
    __syncthreads();
    const int4* idx4 = (const int4*)idx_ws + b * 1024;
#pragma unroll
    for (int i = 0; i < 4; ++i) {
        int4 c = idx4[t + i * 256];
        atomicAdd(&h[c.x], 1); atomicAdd(&h[c.y], 1);
        atomicAdd(&h[c.z], 1); atomicAdd(&h[c.w], 1);
    }
    __syncthreads();
    for (int i = t; i < K_CODES; i += 256) histb[b * K_CODES + i] = h[i];
}

// Pass 2 (1 block, 1024 thr): column prefix over block histograms + global
// exclusive prefix -> cursors (in histb) + goff. Fused Laplace/csn.
__global__ __launch_bounds__(1024) void scan_kernel(
    int* __restrict__ histb, int* __restrict__ goff,
    const float* __restrict__ ema_cs, float* __restrict__ csbuf) {
    __shared__ int pre[K_CODES];
    __shared__ float red[K_CODES];
    int k = threadIdx.x;

    int s = 0;
    for (int b = 0; b < NHB; ++b) {
        int v = histb[b * K_CODES + k];
        histb[b * K_CODES + k] = s;  // local exclusive prefix
        s += v;
    }
    int cnt = s;

    pre[k] = cnt;
    __syncthreads();
    for (int d = 1; d < K_CODES; d <<= 1) {
        int v = (k >= d) ? pre[k - d] : 0;
        __syncthreads();
        if (k >= d) pre[k] += v;
        __syncthreads();
    }
    int base = pre[k] - cnt;
    goff[k] = base;
    if (k == K_CODES - 1) goff[K_CODES] = pre[k];

    for (int b = 0; b < NHB; ++b) histb[b * K_CODES + k] += base;

    float cs = ema_cs[k] * DECAY + OMD * (float)cnt;
    red[k] = cs;
    __syncthreads();
    for (int s2 = 512; s2 > 0; s2 >>= 1) {
        if (k < s2) red[k] += red[k + s2];
        __syncthreads();
    }
    float n = red[0];
    csbuf[k] = (cs + EPS_F) / (n + (float)K_CODES * EPS_F) * n;
}

// Pass 3: scatter row ids into code-sorted order via LDS cursors.
__global__ __launch_bounds__(256) void scatter_kernel(
    const int* __restrict__ idx_ws, const int* __restrict__ histb,
    int* __restrict__ sorted) {
    __shared__ int cur[K_CODES];
    int t = threadIdx.x, b = blockIdx.x;
    for (int i = t; i < K_CODES; i += 256) cur[i] = histb[b * K_CODES + i];
    __syncthreads();
    const int4* idx4 = (const int4*)idx_ws + b * 1024;
#pragma unroll
    for (int i = 0; i < 4; ++i) {
        int4 c = idx4[t + i * 256];
        int r0 = (b * 1024 + t + i * 256) * 4;
        sorted[atomicAdd(&cur[c.x], 1)] = r0 + 0;
        sorted[atomicAdd(&cur[c.y], 1)] = r0 + 1;
        sorted[atomicAdd(&cur[c.z], 1)] = r0 + 2;
        sorted[atomicAdd(&cur[c.w], 1)] = r0 + 3;
    }
}

// Pass 4: one block per code; gather xt rows, LDS tree, fused EMA+normalize.
__global__ __launch_bounds__(256) void dwred_kernel(
    const float* __restrict__ xt, const int* __restrict__ sorted,
    const int* __restrict__ goff, const float* __restrict__ ema_w,
    const float* __restrict__ csbuf, float* __restrict__ new_w) {
    __shared__ int   rows[SEG_CAP];
    __shared__ float red[256];
    int k = blockIdx.x, t = threadIdx.x;
    int base = goff[k];
    int cnt = goff[k + 1] - base;
    int cc = cnt > SEG_CAP ? SEG_CAP : cnt;

    for (int i = t; i < cc; i += 256) rows[i] = sorted[base + i];
    __syncthreads();

    int d = t & 63, sub = t >> 6;
    float a0 = 0.f, a1 = 0.f;
    int i = sub;
    for (; i + 4 < cc; i += 8) {
        a0 += xt[(size_t)rows[i] * D_DIM + d];
        a1 += xt[(size_t)rows[i + 4] * D_DIM + d];
    }
    for (; i < cc; i += 4) a0 += xt[(size_t)rows[i] * D_DIM + d];
    red[t] = a0 + a1;
    __syncthreads();
    if (t < 64) {
        float dwv = red[t] + red[t + 64] + red[t + 128] + red[t + 192];
        new_w[k * D_DIM + t] =
            (ema_w[k * D_DIM + t] * DECAY + OMD * dwv) / csbuf[k];
    }
}

// Gather updated codebook, straight-through output, commitment-loss partials.
// Last block (completion counter) finalizes the loss scalar.
__global__ __launch_bounds__(256) void out_kernel(
    const float* __restrict__ inp, const float* __restrict__ new_w,
    const int* __restrict__ idx_ws, float* __restrict__ out,
    double* __restrict__ loss_acc, int* __restrict__ done_cnt) {
    int row = blockIdx.x * 256 + threadIdx.x;
    int b  = row >> 12;
    int hw = row & (HW - 1);
    const float* xp = inp + (size_t)b * CHW + hw;
    float* op = out + 1 + (size_t)b * CHW + hw;  // out[0] is the loss scalar

    int k = idx_ws[row];
    const float* q = new_w + k * D_DIM;

    float lsum = 0.f;
#pragma unroll
    for (int d = 0; d < D_DIM; ++d) {
        float xv = xp[(size_t)d * HW];
        float qv = q[d];
        float diff = qv - xv;            // stop_gradient(quantized) - x
        lsum = fmaf(diff, diff, lsum);
        op[(size_t)d * HW] = xv + diff;  // x + (quantized - x)
    }

    __shared__ double lred[256];
    lred[threadIdx.x] = (double)lsum;
    __syncthreads();
    for (int s = 128; s > 0; s >>= 1) {
        if (threadIdx.x < s) lred[threadIdx.x] += lred[threadIdx.x + s];
        __syncthreads();
    }
    if (threadIdx.x == 0) {
        atomicAdd(loss_acc, lred[0]);
        __threadfence();
        int old = atomicAdd(done_cnt, 1);
        if (old == (int)gridDim.x - 1) {
            double v = atomicAdd(loss_acc, 0.0);
            out[0] = (float)(0.25 * (v / (double)N_ELEM));
        }
    }
}

extern "C" void kernel_launch(void* const* d_in, const int* in_sizes, int n_in,
                              void* d_out, int out_size, void* d_ws, size_t ws_size,
                              hipStream_t stream) {
    const float* inp    = (const float*)d_in[0];
    const float* weight = (const float*)d_in[1];
    const float* ema_cs = (const float*)d_in[2];
    const float* ema_w  = (const float*)d_in[3];
    float* out = (float*)d_out;

    char* ws = (char*)d_ws;
    double* loss_acc = (double*)(ws + OFF_LOSS);
    int*    flagcnt  = (int*)(ws + OFF_FLAGCNT);
    int*    done_cnt = (int*)(ws + OFF_DONE);
    float*  w2f      = (float*)(ws + OFF_W2F);
    double* w2d      = (double*)(ws + OFF_W2D);
    float*  csbuf    = (float*)(ws + OFF_CS);
    int*    goff     = (int*)(ws + OFF_GOFF);
    float*  new_w    = (float*)(ws + OFF_NEWW);
    int*    idx_ws   = (int*)(ws + OFF_IDX);
    int*    histb    = (int*)(ws + OFF_HISTB);
    int*    sorted   = (int*)(ws + OFF_SORT);
    int*    flaglist = (int*)(ws + OFF_FLAGS);
    short*  wfrag    = (short*)(ws + OFF_WFRAG);

    float* xt        = out + 1;               // scratch: overwritten by out_kernel
    float* out_idx_f = out + 1 + (size_t)N_ELEM;

    prep_kernel<<<36, 256, 0, stream>>>(weight, wfrag, w2f, w2d, (int*)ws);

    argmin_kernel<<<N_ROWS / BROWS, 256, 0, stream>>>(
        inp, wfrag, w2f, idx_ws, out_idx_f, xt, flagcnt, flaglist);

    refine_kernel<<<512, 256, 0, stream>>>(
        xt, weight, w2d, idx_ws, out_idx_f, flagcnt, flaglist);

    hist_kernel<<<NHB, 256, 0, stream>>>(idx_ws, histb);

    scan_kernel<<<1, 1024, 0, stream>>>(histb, goff, ema_cs, csbuf);

    scatter_kernel<<<NHB, 256, 0, stream>>>(idx_ws, histb, sorted);

    dwred_kernel<<<K_CODES, 256, 0, stream>>>(xt, sorted, goff, ema_w, csbuf, new_w);

    out_kernel<<<N_ROWS / 256, 256, 0, stream>>>(inp, new_w, idx_ws, out,
                                                 loss_acc, done_cnt);
}

// Round 9
// 386.745 us; speedup vs baseline: 2.3912x; 1.1209x over previous
//
#include <hip/hip_runtime.h>

// Problem constants (B=64, C=D=64, H=W=64, K=1024)
#define K_CODES 1024
#define D_DIM   64
#define N_ROWS  262144      // B*H*W
#define HW      4096        // H*W
#define CHW     262144      // C*H*W
#define N_ELEM  16777216    // B*C*H*W
#define DECAY   0.99f
#define OMD     0.01f       // 1 - DECAY
#define EPS_F   1e-05f
// Max-domain margin (acc units; dist-gap = 2*acc-gap). Split-bf16 score error
// worst case ~7e-4; margin 1e-3 covers it.
#define MARGIN_ACC 0.001f
#define FLAG_CAP 32768
#define SEG_CAP  2048       // per-code row cap (mean 256, Poisson max ~340)
#define NHB      64         // hist blocks (4096 rows each)
#define BROWS    128        // rows per argmin block (32 per wave)

typedef __attribute__((ext_vector_type(8))) short bf16x8;  // 8 bf16 = 4 VGPRs
typedef __attribute__((ext_vector_type(4))) float f32x4;

// Workspace layout (bytes); [0,64) zeroed by prep. All 16B-aligned.
// FLAGS and WFRAG temporally overlay SORT (dead before scatter writes it).
constexpr size_t OFF_LOSS    = 0;        // 1 double
constexpr size_t OFF_FLAGCNT = 8;        // 1 int
constexpr size_t OFF_DONE    = 12;       // 1 int (out_kernel completion count)
constexpr size_t OFF_W2F     = 64;       // 1024 f   -> 4160
constexpr size_t OFF_W2D     = 4160;     // 1024 d   -> 12352
constexpr size_t OFF_CS      = 12352;    // 1024 f   -> 16448
constexpr size_t OFF_GOFF    = 16448;    // 1025 i   -> 20608 (padded)
constexpr size_t OFF_NEWW    = 282752;   // 65536 f  -> 544896
constexpr size_t OFF_IDX     = 544896;   // 262144 i -> 1593472
constexpr size_t OFF_HISTB   = 1593472;  // 64x1024 i -> 1855616
constexpr size_t OFF_SORT    = 1855616;  // 262144 i -> 2904192
constexpr size_t OFF_FLAGS   = 1855616;  // 32768 i (dead after refine)
constexpr size_t OFF_WFRAG   = 1986688;  // 131072 bf16 (dead after argmin)

__device__ __forceinline__ short f2bf(float f) {  // RNE float->bf16
    unsigned u = __float_as_uint(f);
    u += 0x7fffu + ((u >> 16) & 1u);
    return (short)(u >> 16);
}
__device__ __forceinline__ float bf2f(short h) {
    return __uint_as_float(((unsigned)(unsigned short)h) << 16);
}

__device__ __forceinline__ void gload_lds16(const float4* g, void* l) {
    __builtin_amdgcn_global_load_lds(
        (const __attribute__((address_space(1))) void*)g,
        (__attribute__((address_space(3))) void*)l, 16, 0, 0);
}

// One-time prep: W swizzled to bf16 hi/lo B-fragment pairs for 16x16x32 MFMA.
// Block 35 threads 0..3 zero the scalar counters.
__global__ __launch_bounds__(256) void prep_kernel(
    const float* __restrict__ w, short* __restrict__ wfrag,
    float* __restrict__ w2f, double* __restrict__ w2d,
    int* __restrict__ zero16) {
    int t = threadIdx.x;
    if (blockIdx.x == 35 && t < 4) zero16[t] = 0;
    if (blockIdx.x < 32) {
        int gid = blockIdx.x * 256 + t;  // (j<<7)|(h<<6)|L
        int j = gid >> 7, h = (gid >> 6) & 1, L = gid & 63;
        int code = j * 16 + (L & 15);
        int kb = h * 32 + ((L >> 4) << 3);
        const float* wp = w + code * D_DIM + kb;
        short hi[8], lo[8];
#pragma unroll
        for (int i = 0; i < 8; ++i) {
            float v = wp[i];
            short hb = f2bf(v);
            hi[i] = hb;
            lo[i] = f2bf(v - bf2f(hb));
        }
        short* dh = wfrag + (size_t)(((j * 2 + h) * 2 + 0) * 64 + L) * 8;
        short* dl = wfrag + (size_t)(((j * 2 + h) * 2 + 1) * 64 + L) * 8;
#pragma unroll
        for (int i = 0; i < 8; ++i) { dh[i] = hi[i]; dl[i] = lo[i]; }
    } else {
        int k = (blockIdx.x - 32) * 256 + t;
        const float* wk = w + k * D_DIM;
        float sf = 0.f; double sd = 0.0;
#pragma unroll
        for (int d = 0; d < D_DIM; ++d) {
            float wv = wk[d];
            sf = fmaf(wv, wv, sf);
            sd = fma((double)wv, (double)wv, sd);
        }
        w2f[k] = sf; w2d[k] = sd;
    }
}

// Split-bf16 MFMA argmin (R7, proven 124us): 32 rows/wave, 128/block,
// 4 blocks/CU, max-domain accumulator init, exact cndmask index tracking.
__global__ __launch_bounds__(256) __attribute__((amdgpu_waves_per_eu(2, 4)))
void argmin_kernel(
    const float* __restrict__ inp, const short* __restrict__ wfrag,
    const float* __restrict__ w2f, int* __restrict__ idx_ws,
    float* __restrict__ out_idx_f, float* __restrict__ xt,
    int* __restrict__ flagcnt, int* __restrict__ flaglist) {
    __shared__ float w2s[K_CODES];
    __shared__ alignas(16) char smem_u[64 * 68 * 4];  // xs(17408B) / bufB(16KB) union
    __shared__ alignas(16) short bufA[8192];          // 16 KB
    float (*xs)[68] = (float (*)[68])smem_u;          // +4 pad per row
    short* bufB = (short*)smem_u;

    int t = threadIdx.x;
    ((float4*)w2s)[t] = ((const float4*)w2f)[t];

    int rowbase = blockIdx.x * BROWS;
    int b = rowbase >> 12, hwb = rowbase & (HW - 1);
    const float* xp = inp + (size_t)b * CHW + hwb;
    int lane = t & 63, wave = t >> 6;
    int q = lane >> 4, col = lane & 15;

    bf16x8 aH[2][2], aL[2][2];  // [row-set][k-half]; built in owning pass

    for (int p = 0; p < 2; ++p) {
#pragma unroll
        for (int it = 0; it < 16; ++it) {
            int d = wave * 16 + it;
            xs[lane][d] = xp[(size_t)d * HW + p * 64 + lane];  // coalesced 256B
        }
        __syncthreads();

        float4* xt4 = (float4*)(xt + (size_t)(rowbase + p * 64) * D_DIM);
#pragma unroll
        for (int i2 = 0; i2 < 4; ++i2) {
            int c2 = t + i2 * 256;
            xt4[c2] = ((const float4*)xs[c2 >> 4])[c2 & 15];
        }

        if ((wave >> 1) == p) {
#pragma unroll
            for (int s2 = 0; s2 < 2; ++s2) {
                int rl = (wave & 1) * 32 + s2 * 16 + col;
#pragma unroll
                for (int h = 0; h < 2; ++h) {
#pragma unroll
                    for (int i = 0; i < 8; ++i) {
                        float v = xs[rl][h * 32 + q * 8 + i];
                        short hb = f2bf(v);
                        aH[s2][h][i] = hb;
                        aL[s2][h][i] = f2bf(v - bf2f(hb));
                    }
                }
            }
        }
        __syncthreads();
    }

    float best[2][4], best2[2][4];
    int   bj[2][4];
#pragma unroll
    for (int s2 = 0; s2 < 2; ++s2)
#pragma unroll
        for (int r = 0; r < 4; ++r) {
            best[s2][r] = -3.4e38f; best2[s2][r] = -3.4e38f; bj[s2][r] = 0;
        }
    const float4* wsrc = (const float4*)wfrag;

    {
        const float4* src = wsrc + t;
        char* nb = (char*)bufA + wave * 1024;
#pragma unroll
        for (int i2 = 0; i2 < 4; ++i2)
            gload_lds16(src + i2 * 256, nb + i2 * 4096);
    }

    for (int st = 0; st < 16; ++st) {
        asm volatile("s_waitcnt vmcnt(0)" ::: "memory");
        __syncthreads();
        if (st < 15) {
            const float4* src = wsrc + (size_t)(st + 1) * 1024 + t;
            char* nb = ((st & 1) ? (char*)bufA : (char*)bufB) + wave * 1024;
#pragma unroll
            for (int i2 = 0; i2 < 4; ++i2)
                gload_lds16(src + i2 * 256, nb + i2 * 4096);
        }
        const bf16x8* wt = (const bf16x8*)((st & 1) ? bufB : bufA);

#pragma unroll
        for (int jp = 0; jp < 2; ++jp) {
            int jA = st * 4 + jp * 2, jB = jA + 1;
            int jjA = jp * 2, jjB = jp * 2 + 1;
            bf16x8 bh0A = wt[(jjA * 4 + 0) * 64 + lane];
            bf16x8 bl0A = wt[(jjA * 4 + 1) * 64 + lane];
            bf16x8 bh1A = wt[(jjA * 4 + 2) * 64 + lane];
            bf16x8 bl1A = wt[(jjA * 4 + 3) * 64 + lane];
            bf16x8 bh0B = wt[(jjB * 4 + 0) * 64 + lane];
            bf16x8 bl0B = wt[(jjB * 4 + 1) * 64 + lane];
            bf16x8 bh1B = wt[(jjB * 4 + 2) * 64 + lane];
            bf16x8 bl1B = wt[(jjB * 4 + 3) * 64 + lane];
            float cA = -0.5f * w2s[jA * 16 + col];
            float cB = -0.5f * w2s[jB * 16 + col];
            f32x4 a0A = {cA, cA, cA, cA}, a1A = {cA, cA, cA, cA};
            f32x4 a0B = {cB, cB, cB, cB}, a1B = {cB, cB, cB, cB};
            a0A = __builtin_amdgcn_mfma_f32_16x16x32_bf16(aL[0][0], bh0A, a0A, 0, 0, 0);
            a1A = __builtin_amdgcn_mfma_f32_16x16x32_bf16(aL[1][0], bh0A, a1A, 0, 0, 0);
            a0B = __builtin_amdgcn_mfma_f32_16x16x32_bf16(aL[0][0], bh0B, a0B, 0, 0, 0);
            a1B = __builtin_amdgcn_mfma_f32_16x16x32_bf16(aL[1][0], bh0B, a1B, 0, 0, 0);
            a0A = __builtin_amdgcn_mfma_f32_16x16x32_bf16(aL[0][1], bh1A, a0A, 0, 0, 0);
            a1A = __builtin_amdgcn_mfma_f32_16x16x32_bf16(aL[1][1], bh1A, a1A, 0, 0, 0);
            a0B = __builtin_amdgcn_mfma_f32_16x16x32_bf16(aL[0][1], bh1B, a0B, 0, 0, 0);
            a1B = __builtin_amdgcn_mfma_f32_16x16x32_bf16(aL[1][1], bh1B, a1B, 0, 0, 0);
            a0A = __builtin_amdgcn_mfma_f32_16x16x32_bf16(aH[0][0], bl0A, a0A, 0, 0, 0);
            a1A = __builtin_amdgcn_mfma_f32_16x16x32_bf16(aH[1][0], bl0A, a1A, 0, 0, 0);
            a0B = __builtin_amdgcn_mfma_f32_16x16x32_bf16(aH[0][0], bl0B, a0B, 0, 0, 0);
            a1B = __builtin_amdgcn_mfma_f32_16x16x32_bf16(aH[1][0], bl0B, a1B, 0, 0, 0);
            a0A = __builtin_amdgcn_mfma_f32_16x16x32_bf16(aH[0][1], bl1A, a0A, 0, 0, 0);
            a1A = __builtin_amdgcn_mfma_f32_16x16x32_bf16(aH[1][1], bl1A, a1A, 0, 0, 0);
            a0B = __builtin_amdgcn_mfma_f32_16x16x32_bf16(aH[0][1], bl1B, a0B, 0, 0, 0);
            a1B = __builtin_amdgcn_mfma_f32_16x16x32_bf16(aH[1][1], bl1B, a1B, 0, 0, 0);
            a0A = __builtin_amdgcn_mfma_f32_16x16x32_bf16(aH[0][0], bh0A, a0A, 0, 0, 0);
            a1A = __builtin_amdgcn_mfma_f32_16x16x32_bf16(aH[1][0], bh0A, a1A, 0, 0, 0);
            a0B = __builtin_amdgcn_mfma_f32_16x16x32_bf16(aH[0][0], bh0B, a0B, 0, 0, 0);
            a1B = __builtin_amdgcn_mfma_f32_16x16x32_bf16(aH[1][0], bh0B, a1B, 0, 0, 0);
            a0A = __builtin_amdgcn_mfma_f32_16x16x32_bf16(aH[0][1], bh1A, a0A, 0, 0, 0);
            a1A = __builtin_amdgcn_mfma_f32_16x16x32_bf16(aH[1][1], bh1A, a1A, 0, 0, 0);
            a0B = __builtin_amdgcn_mfma_f32_16x16x32_bf16(aH[0][1], bh1B, a0B, 0, 0, 0);
            a1B = __builtin_amdgcn_mfma_f32_16x16x32_bf16(aH[1][1], bh1B, a1B, 0, 0, 0);
#pragma unroll
            for (int s2 = 0; s2 < 2; ++s2) {
#pragma unroll
                for (int r = 0; r < 4; ++r) {
                    float vA = (s2 ? a1A : a0A)[r];
                    float vB = (s2 ? a1B : a0B)[r];
                    bool gA = vA > best[s2][r];
                    best2[s2][r] = fmaxf(best2[s2][r], fminf(best[s2][r], vA));
                    best[s2][r]  = fmaxf(best[s2][r], vA);
                    bj[s2][r]    = gA ? jA : bj[s2][r];
                    bool gB = vB > best[s2][r];
                    best2[s2][r] = fmaxf(best2[s2][r], fminf(best[s2][r], vB));
                    best[s2][r]  = fmaxf(best[s2][r], vB);
                    bj[s2][r]    = gB ? jB : bj[s2][r];
                }
            }
        }
    }

    int bk[2][4];
#pragma unroll
    for (int s2 = 0; s2 < 2; ++s2)
#pragma unroll
        for (int r = 0; r < 4; ++r)
            bk[s2][r] = (bj[s2][r] << 4) | col;

#pragma unroll
    for (int m = 1; m < 16; m <<= 1) {
#pragma unroll
        for (int s2 = 0; s2 < 2; ++s2) {
#pragma unroll
            for (int r = 0; r < 4; ++r) {
                float ob  = __shfl_xor(best[s2][r], m, 64);
                float ob2 = __shfl_xor(best2[s2][r], m, 64);
                int   obk = __shfl_xor(bk[s2][r], m, 64);
                float nb2 = fmaxf(fmaxf(best2[s2][r], ob2),
                                  fminf(best[s2][r], ob));
                int   nbk = ob > best[s2][r] ? obk
                            : (best[s2][r] > ob ? bk[s2][r]
                                                : min(bk[s2][r], obk));
                best[s2][r]  = fmaxf(best[s2][r], ob);
                best2[s2][r] = nb2;
                bk[s2][r]    = nbk;
            }
        }
    }

    if (col == 0) {
#pragma unroll
        for (int s2 = 0; s2 < 2; ++s2) {
#pragma unroll
            for (int r = 0; r < 4; ++r) {
                int row = rowbase + wave * 32 + s2 * 16 + q * 4 + r;
                idx_ws[row]    = bk[s2][r];
                out_idx_f[row] = (float)bk[s2][r];
                if (best[s2][r] - best2[s2][r] < MARGIN_ACC) {
                    int pos = atomicAdd(flagcnt, 1);
                    if (pos < FLAG_CAP) flaglist[pos] = row;
                }
            }
        }
    }
}

// fp64 rescan of flagged rows (exact); wave-per-row.
__global__ __launch_bounds__(256) void refine_kernel(
    const float* __restrict__ xt, const float* __restrict__ weight,
    const double* __restrict__ w2d, int* __restrict__ idx_ws,
    float* __restrict__ out_idx_f, const int* __restrict__ flagcnt,
    const int* __restrict__ flaglist) {
    __shared__ float sx[4][64];
    int cnt = *flagcnt;
    if (cnt > FLAG_CAP) cnt = FLAG_CAP;
    int t = threadIdx.x, lane = t & 63, wave = t >> 6;

    for (int r = blockIdx.x * 4 + wave; r < cnt; r += gridDim.x * 4) {
        int row = flaglist[r];
        sx[wave][lane] = xt[(size_t)row * D_DIM + lane];
        asm volatile("s_waitcnt lgkmcnt(0)" ::: "memory");

        double bd = 1.0e300; int bi = 0;
        int k0 = lane * 16;
#pragma unroll 4
        for (int c = 0; c < 16; ++c) {
            int k = k0 + c;
            const float4* wk4 = (const float4*)(weight + (size_t)k * D_DIM);
            double dot = 0.0;
#pragma unroll
            for (int d4 = 0; d4 < 16; ++d4) {
                float4 wv = wk4[d4];
                dot = fma((double)wv.x, (double)sx[wave][d4 * 4 + 0], dot);
                dot = fma((double)wv.y, (double)sx[wave][d4 * 4 + 1], dot);
                dot = fma((double)wv.z, (double)sx[wave][d4 * 4 + 2], dot);
                dot = fma((double)wv.w, (double)sx[wave][d4 * 4 + 3], dot);
            }
            double dist = w2d[k] - 2.0 * dot;  // x^2 omitted (row-constant)
            if (dist < bd) { bd = dist; bi = k; }
        }
#pragma unroll
        for (int m = 1; m < 64; m <<= 1) {
            double od = __shfl_xor(bd, m, 64);
            int    oi = __shfl_xor(bi, m, 64);
            if (od < bd || (od == bd && oi < bi)) { bd = od; bi = oi; }
        }
        if (lane == 0 && bi != idx_ws[row]) {
            idx_ws[row]    = bi;
            out_idx_f[row] = (float)bi;
        }
    }
}

// Counting sort, pass 1: per-block LDS histogram of 4096 rows -> histb[b][k].
// R9: 1024 threads (1 int4 each) — 4x less serial work per thread.
__global__ __launch_bounds__(1024) void hist_kernel(
    const int* __restrict__ idx_ws, int* __restrict__ histb) {
    __shared__ int h[K_CODES];
    int t = threadIdx.x, b = blockIdx.x;
    h[t] = 0;
    __syncthreads();
    int4 c = ((const int4*)idx_ws)[b * 1024 + t];
    atomicAdd(&h[c.x], 1); atomicAdd(&h[c.y], 1);
    atomicAdd(&h[c.z], 1); atomicAdd(&h[c.w], 1);
    __syncthreads();
    histb[b * K_CODES + t] = h[t];
}

// Pass 2 (1 block, 1024 thr): column prefix over block histograms + global
// exclusive prefix -> cursors (in histb) + goff. Fused Laplace/csn.
// (Walks are coalesced across threads: for fixed b, threads k read 4KB
// contiguous.)
__global__ __launch_bounds__(1024) void scan_kernel(
    int* __restrict__ histb, int* __restrict__ goff,
    const float* __restrict__ ema_cs, float* __restrict__ csbuf) {
    __shared__ int pre[K_CODES];
    __shared__ float red[K_CODES];
    int k = threadIdx.x;

    int s = 0;
    for (int b = 0; b < NHB; ++b) {
        int v = histb[b * K_CODES + k];
        histb[b * K_CODES + k] = s;  // local exclusive prefix
        s += v;
    }
    int cnt = s;

    pre[k] = cnt;
    __syncthreads();
    for (int d = 1; d < K_CODES; d <<= 1) {
        int v = (k >= d) ? pre[k - d] : 0;
        __syncthreads();
        if (k >= d) pre[k] += v;
        __syncthreads();
    }
    int base = pre[k] - cnt;
    goff[k] = base;
    if (k == K_CODES - 1) goff[K_CODES] = pre[k];

    for (int b = 0; b < NHB; ++b) histb[b * K_CODES + k] += base;

    float cs = ema_cs[k] * DECAY + OMD * (float)cnt;
    red[k] = cs;
    __syncthreads();
    for (int s2 = 512; s2 > 0; s2 >>= 1) {
        if (k < s2) red[k] += red[k + s2];
        __syncthreads();
    }
    float n = red[0];
    csbuf[k] = (cs + EPS_F) / (n + (float)K_CODES * EPS_F) * n;
}

// Pass 3: scatter row ids into code-sorted order via LDS cursors.
// R9: 1024 threads (1 int4 each).
__global__ __launch_bounds__(1024) void scatter_kernel(
    const int* __restrict__ idx_ws, const int* __restrict__ histb,
    int* __restrict__ sorted) {
    __shared__ int cur[K_CODES];
    int t = threadIdx.x, b = blockIdx.x;
    cur[t] = histb[b * K_CODES + t];
    __syncthreads();
    int4 c = ((const int4*)idx_ws)[b * 1024 + t];
    int r0 = (b * 1024 + t) * 4;
    sorted[atomicAdd(&cur[c.x], 1)] = r0 + 0;
    sorted[atomicAdd(&cur[c.y], 1)] = r0 + 1;
    sorted[atomicAdd(&cur[c.z], 1)] = r0 + 2;
    sorted[atomicAdd(&cur[c.w], 1)] = r0 + 3;
}

// Pass 4: one block per code; gather xt rows, LDS tree, fused EMA+normalize.
// R9: 512 threads -> 8 independent row chains/block, 32 waves/CU (was 16) —
// doubles the outstanding-load budget of the random 256B row gather.
__global__ __launch_bounds__(512) void dwred_kernel(
    const float* __restrict__ xt, const int* __restrict__ sorted,
    const int* __restrict__ goff, const float* __restrict__ ema_w,
    const float* __restrict__ csbuf, float* __restrict__ new_w) {
    __shared__ int   rows[SEG_CAP];
    __shared__ float red[512];
    int k = blockIdx.x, t = threadIdx.x;
    int base = goff[k];
    int cnt = goff[k + 1] - base;
    int cc = cnt > SEG_CAP ? SEG_CAP : cnt;

    for (int i = t; i < cc; i += 512) rows[i] = sorted[base + i];
    __syncthreads();

    int d = t & 63, sub = t >> 6;  // 8 sub-chains
    float a0 = 0.f, a1 = 0.f;
    int i = sub;
    for (; i + 8 < cc; i += 16) {
        a0 += xt[(size_t)rows[i] * D_DIM + d];
        a1 += xt[(size_t)rows[i + 8] * D_DIM + d];
    }
    for (; i < cc; i += 8) a0 += xt[(size_t)rows[i] * D_DIM + d];
    red[t] = a0 + a1;
    __syncthreads();
    if (t < 64) {
        float dwv = red[t] + red[t + 64] + red[t + 128] + red[t + 192] +
                    red[t + 256] + red[t + 320] + red[t + 384] + red[t + 448];
        new_w[k * D_DIM + t] =
            (ema_w[k * D_DIM + t] * DECAY + OMD * dwv) / csbuf[k];
    }
}

// Gather updated codebook, straight-through output, commitment-loss partials.
// Last block (completion counter) finalizes the loss scalar.
__global__ __launch_bounds__(256) void out_kernel(
    const float* __restrict__ inp, const float* __restrict__ new_w,
    const int* __restrict__ idx_ws, float* __restrict__ out,
    double* __restrict__ loss_acc, int* __restrict__ done_cnt) {
    int row = blockIdx.x * 256 + threadIdx.x;
    int b  = row >> 12;
    int hw = row & (HW - 1);
    const float* xp = inp + (size_t)b * CHW + hw;
    float* op = out + 1 + (size_t)b * CHW + hw;  // out[0] is the loss scalar

    int k = idx_ws[row];
    const float* q = new_w + k * D_DIM;

    float lsum = 0.f;
#pragma unroll
    for (int d = 0; d < D_DIM; ++d) {
        float xv = xp[(size_t)d * HW];
        float qv = q[d];
        float diff = qv - xv;            // stop_gradient(quantized) - x
        lsum = fmaf(diff, diff, lsum);
        op[(size_t)d * HW] = xv + diff;  // x + (quantized - x)
    }

    __shared__ double lred[256];
    lred[threadIdx.x] = (double)lsum;
    __syncthreads();
    for (int s = 128; s > 0; s >>= 1) {
        if (threadIdx.x < s) lred[threadIdx.x] += lred[threadIdx.x + s];
        __syncthreads();
    }
    if (threadIdx.x == 0) {
        atomicAdd(loss_acc, lred[0]);
        __threadfence();
        int old = atomicAdd(done_cnt, 1);
        if (old == (int)gridDim.x - 1) {
            double v = atomicAdd(loss_acc, 0.0);
            out[0] = (float)(0.25 * (v / (double)N_ELEM));
        }
    }
}

extern "C" void kernel_launch(void* const* d_in, const int* in_sizes, int n_in,
                              void* d_out, int out_size, void* d_ws, size_t ws_size,
                              hipStream_t stream) {
    const float* inp    = (const float*)d_in[0];
    const float* weight = (const float*)d_in[1];
    const float* ema_cs = (const float*)d_in[2];
    const float* ema_w  = (const float*)d_in[3];
    float* out = (float*)d_out;

    char* ws = (char*)d_ws;
    double* loss_acc = (double*)(ws + OFF_LOSS);
    int*    flagcnt  = (int*)(ws + OFF_FLAGCNT);
    int*    done_cnt = (int*)(ws + OFF_DONE);
    float*  w2f      = (float*)(ws + OFF_W2F);
    double* w2d      = (double*)(ws + OFF_W2D);
    float*  csbuf    = (float*)(ws + OFF_CS);
    int*    goff     = (int*)(ws + OFF_GOFF);
    float*  new_w    = (float*)(ws + OFF_NEWW);
    int*    idx_ws   = (int*)(ws + OFF_IDX);
    int*    histb    = (int*)(ws + OFF_HISTB);
    int*    sorted   = (int*)(ws + OFF_SORT);
    int*    flaglist = (int*)(ws + OFF_FLAGS);
    short*  wfrag    = (short*)(ws + OFF_WFRAG);

    float* xt        = out + 1;               // scratch: overwritten by out_kernel
    float* out_idx_f = out + 1 + (size_t)N_ELEM;

    prep_kernel<<<36, 256, 0, stream>>>(weight, wfrag, w2f, w2d, (int*)ws);

    argmin_kernel<<<N_ROWS / BROWS, 256, 0, stream>>>(
        inp, wfrag, w2f, idx_ws, out_idx_f, xt, flagcnt, flaglist);

    refine_kernel<<<1024, 256, 0, stream>>>(
        xt, weight, w2d, idx_ws, out_idx_f, flagcnt, flaglist);

    hist_kernel<<<NHB, 1024, 0, stream>>>(idx_ws, histb);

    scan_kernel<<<1, 1024, 0, stream>>>(histb, goff, ema_cs, csbuf);

    scatter_kernel<<<NHB, 1024, 0, stream>>>(idx_ws, histb, sorted);

    dwred_kernel<<<K_CODES, 512, 0, stream>>>(xt, sorted, goff, ema_w, csbuf, new_w);

    out_kernel<<<N_ROWS / 256, 256, 0, stream>>>(inp, new_w, idx_ws, out,
                                                 loss_acc, done_cnt);
}